// Round 8
// baseline (276.558 us; speedup 1.0000x reference)
//
#include <hip/hip_runtime.h>
#include <cstdint>
#include <cstddef>

#define NN   50000
#define FIN  128
#define HD   128
#define EE   800000
#define C3   384   // 3*H
#define NOUT 40

#define NBLK ((NN + 127) / 128)                     // 391 row-blocks

#define NBUCK ((NN + 511) / 512)                    // 98 coarse dst-buckets
#define BCAP  16384                                 // per-bucket ebuf capacity
#define BK_BLKS ((EE + 8191) / 8192)                // 98 bucketing blocks
#define SCAP  12288                                 // csr staging (max ~9.2k)
#define SXB   ((NN + 16) / 16)                      // 3126 split_x blocks (16 nodes, incl ZROW)

#define RCAP      132                               // per-dst record slots (LDS)
#define STORE_CAP 128                               // fast-path record cap
#define ZROW NN                                     // zeroed xb row for pad records

#define LDSW 132   // padded epilogue LDS row stride (ushorts)
#define A2W  136   // gemm23 a2 LDS row stride (16B-aligned rows, 2-way banks)

typedef __attribute__((ext_vector_type(8))) short s8v;   // 8 x bf16 (4 VGPR)
typedef __attribute__((ext_vector_type(4))) float f4v;   // MFMA acc
typedef __attribute__((ext_vector_type(8))) ushort u8v;  // 8 x bf16 (16B)

typedef const __attribute__((address_space(1))) unsigned int* guintp;
typedef __attribute__((address_space(3))) unsigned int* luintp;

static __device__ __forceinline__ void async_copy16(const void* g, void* l) {
    __builtin_amdgcn_global_load_lds((guintp)g, (luintp)l, 16, 0, 0);
}

// ---------- bf16 helpers ----------
static __device__ __forceinline__ float b2f(ushort u) {
    return __uint_as_float((unsigned)u << 16);
}
static __device__ __forceinline__ ushort f2b(float v) {
    unsigned u = __float_as_uint(v);
    unsigned r = u + 0x7fffu + ((u >> 16) & 1u);
    return (ushort)(r >> 16);
}

// ---------- merged: edge bucket sort + weight transposes + att fold ----------
// blocks [0,98): bucket sort; blocks [98,915): weight prep (independent work).
__global__ __launch_bounds__(1024) void k_bucketw(
    const int* __restrict__ e_src, const int* __restrict__ e_dst,
    int* __restrict__ bcnt, uint* __restrict__ ebuf,
    const float* __restrict__ Wg, const float* __restrict__ Wc,
    const float* __restrict__ Wl, const float* __restrict__ Wr,
    const float* __restrict__ W1, const float* __restrict__ W2,
    const float* __restrict__ W3,
    const float* __restrict__ asv, const float* __restrict__ adv,
    float* __restrict__ w_as, float* __restrict__ w_ad,
    ushort* __restrict__ btg, ushort* __restrict__ btc,
    ushort* __restrict__ btsg,
    ushort* __restrict__ bt1, ushort* __restrict__ bt2,
    ushort* __restrict__ bt3)
{
    int t = threadIdx.x;
    if (blockIdx.x >= BK_BLKS) {
        int ry = blockIdx.x - BK_BLKS;
        if (ry == 816) {
            if (t < 128) {
                float s1 = 0.f, s2 = 0.f;
                for (int j = 0; j < 128; ++j) {
                    float w = Wg[t * 128 + j];
                    s1 += w * asv[j];
                    s2 += w * adv[j];
                }
                w_as[t] = s1; w_ad[t] = s2;
            }
            return;
        }
        const float* W = nullptr; ushort* dh; int K, Nw, n;
        bool sage = false;
        if (ry < 128)      { n = ry;       K = 128; Nw = 128; W = Wg; dh = btg; }
        else if (ry < 256) { n = ry - 128; K = 128; Nw = 128; W = Wc; dh = btc; }
        else if (ry < 384) { n = ry - 256; K = 256; Nw = 128; sage = true; dh = btsg; }
        else if (ry < 640) { n = ry - 384; K = 384; Nw = 256; W = W1; dh = bt1; }
        else if (ry < 768) { n = ry - 640; K = 256; Nw = 128; W = W2; dh = bt2; }
        else               { n = ry - 768; K = 128; Nw = 40;  W = W3; dh = bt3; }
        for (int k = t; k < K; k += 1024) {
            float v;
            if (sage) v = (k < 128) ? Wl[(size_t)k * 128 + n] : Wr[(size_t)(k - 128) * 128 + n];
            else      v = (n < Nw) ? W[(size_t)k * Nw + n] : 0.f;
            dh[(size_t)n * K + k] = f2b(v);
        }
        return;
    }
    __shared__ uint sval[8192];          // 32 KB staged packed edges
    __shared__ int scnt[NBUCK], sbase[NBUCK];
    if (t < NBUCK) scnt[t] = 0;
    __syncthreads();
    int e0 = blockIdx.x * 8192;
    #pragma unroll
    for (int i = 0; i < 8; ++i) {
        int g = e0 + i * 1024 + t;
        uint val = 0xffffffffu;          // sentinel (bucket 127 >= NBUCK)
        if (g < EE) {
            int d = e_dst[g];
            int s = e_src[g];
            int b = d >> 9;
            val = ((uint)b << 25) | ((uint)(d & 511) << 16) | (uint)s;
            atomicAdd(&scnt[b], 1);
        }
        sval[i * 1024 + t] = val;
    }
    __syncthreads();
    if (t < NBUCK) {
        sbase[t] = atomicAdd(&bcnt[t], scnt[t]);   // reserve contiguous run
        scnt[t] = 0;                                // reuse as local cursor
    }
    __syncthreads();
    #pragma unroll
    for (int i = 0; i < 8; ++i) {
        uint val = sval[i * 1024 + t];
        if (val != 0xffffffffu) {
            int b = val >> 25;
            int lo = atomicAdd(&scnt[b], 1);
            ebuf[(size_t)b * BCAP + sbase[b] + lo] = val;
        }
    }
}

// ---------- merged: (deg-hist + scan + in-LDS CSR scatter) AND x-split ----------
__global__ __launch_bounds__(1024) void k_csrx(
    const int* __restrict__ bcnt, const uint* __restrict__ ebuf,
    int* __restrict__ offs, float* __restrict__ dinv,
    ushort* __restrict__ esrc,
    const float* __restrict__ x,
    const float* __restrict__ w_as, const float* __restrict__ w_ad,
    ushort* __restrict__ xb, float* __restrict__ a_s, float* __restrict__ a_d)
{
    int t = threadIdx.x;
    if (blockIdx.x >= NBUCK) {
        int node = (blockIdx.x - NBUCK) * 16 + (t >> 6);
        if (node > NN) return;
        int lane = t & 63;
        size_t o = (size_t)node * 128 + lane * 2;
        if (node == NN) {                // ZROW: all-zero pad row
            ushort2 z; z.x = 0; z.y = 0;
            *(ushort2*)(xb + o) = z;
            return;
        }
        float2 v  = *(const float2*)(x + o);
        { ushort2 u; u.x = f2b(v.x); u.y = f2b(v.y); *(ushort2*)(xb + o) = u; }
        float2 w1 = *(const float2*)(w_as + lane * 2);
        float2 w2 = *(const float2*)(w_ad + lane * 2);
        float s1 = v.x * w1.x + v.y * w1.y;
        float s2 = v.x * w2.x + v.y * w2.y;
        #pragma unroll
        for (int off = 32; off; off >>= 1) {
            s1 += __shfl_down(s1, off);
            s2 += __shfl_down(s2, off);
        }
        if (lane == 0) { a_s[node] = s1; a_d[node] = s2; }
        return;
    }
    __shared__ ushort sout[SCAP];        // 24 KB staging
    __shared__ int hist[512];            // degree hist, reused as cursors
    __shared__ int sh[256];
    __shared__ int btop_s;
    int b = blockIdx.x;
    int d0 = b * 512;
    int ndst = NN - d0; if (ndst > 512) ndst = 512;
    if (t < 512) hist[t] = 0;
    __syncthreads();
    int nb = bcnt[b];
    const uint* eb = ebuf + (size_t)b * BCAP;
    for (int i = t; i < nb; i += 1024)
        atomicAdd(&hist[(eb[i] >> 16) & 511], 1);
    __syncthreads();
    if (t < 64) {                        // top-level exclusive prefix for bucket b
        int acc = 0;
        for (int i = t; i < b; i += 64) {
            int nd = NN - i * 512; if (nd > 512) nd = 512;
            acc += bcnt[i] + nd;
        }
        #pragma unroll
        for (int off = 32; off; off >>= 1) acc += __shfl_down(acc, off);
        if (t == 0) btop_s = acc;
    }
    int v0 = 0, v1 = 0;
    if (t < 256) {
        int i0g = d0 + t * 2;
        v0 = (i0g < NN) ? hist[t * 2] + 1 : 0;
        v1 = (i0g + 1 < NN) ? hist[t * 2 + 1] + 1 : 0;
        sh[t] = v0 + v1;
    }
    __syncthreads();
    for (int off = 1; off < 256; off <<= 1) {
        int u = 0;
        if (t < 256 && t >= off) u = sh[t - off];
        __syncthreads();
        if (t < 256) sh[t] += u;
        __syncthreads();
    }
    if (t < 256) {
        int pair = v0 + v1;
        int lex = sh[t] - pair;          // bucket-local exclusive
        int excl = lex + btop_s;
        int i0g = d0 + t * 2;
        if (i0g < NN) {
            offs[i0g] = excl; dinv[i0g] = rsqrtf((float)v0);
            hist[t * 2] = lex;           // cursor (hist value consumed above)
        }
        if (i0g + 1 < NN) {
            offs[i0g + 1] = excl + v0; dinv[i0g + 1] = rsqrtf((float)v1);
            hist[t * 2 + 1] = lex + v0;
        }
        if (b == NBUCK - 1 && t == 255) offs[NN] = excl + pair;
    }
    __syncthreads();
    for (int i = t; i < nb; i += 1024) {
        uint val = eb[i];
        int slot = atomicAdd(&hist[(val >> 16) & 511], 1);
        sout[slot] = (ushort)(val & 0xffffu);
    }
    if (t < ndst) {                      // self loops
        int slot = atomicAdd(&hist[t], 1);
        sout[slot] = (ushort)(d0 + t);
    }
    __syncthreads();
    int total = nb + ndst;
    int obase = btop_s;
    for (int i = t; i < total; i += 1024)
        esrc[obase + i] = sout[i];       // contiguous full-line writes
}

// ---------- CSR gather: 16-lane quads, 2-deep dual-body (no spill) ----------
__global__ __launch_bounds__(256) void k_gather(
    const ushort* __restrict__ esrc, const int* __restrict__ offs,
    const float* __restrict__ a_s, const float* __restrict__ a_d,
    const float* __restrict__ dinv,
    const ushort* __restrict__ xb,
    ushort* __restrict__ tgb, ushort* __restrict__ tcb,
    ushort* __restrict__ tsb)
{
    __shared__ uint2 recs[16][RCAP];     // 16.5 KB: per-quad edge records
    int t = threadIdx.x;
    int qid = t >> 4;
    int ln = t & 15;
    int d = blockIdx.x * 16 + qid;
    if (d >= NN) return;
    uint2* rec = recs[qid];
    int beg = offs[d], end = offs[d + 1];
    int cnt = end - beg;
    float ad = a_d[d], dd = dinv[d];
    int stored = cnt < STORE_CAP ? cnt : STORE_CAP;

    // ---- phase A: e + wc into records, track max ----
    float mloc = -3.0e38f;
    for (int b = 0; b < cnt; b += 16) {
        int j = b + ln;
        if (j < cnt) {
            int s = esrc[beg + j];
            float e = a_s[s] + ad;
            e = (e > 0.f) ? e : 0.2f * e;
            mloc = fmaxf(mloc, e);
            if (j < STORE_CAP) {
                uint2 r;
                r.x = __float_as_uint(e);
                r.y = (uint)s | ((uint)f2b(dinv[s] * dd) << 16);
                rec[j] = r;
            }
        }
    }
    float m = mloc;
    #pragma unroll
    for (int off = 1; off < 16; off <<= 1) m = fmaxf(m, __shfl_xor(m, off, 16));

    // ---- phase B: exp + denom ----
    float denl = 0.f;
    for (int j = ln; j < stored; j += 16) {
        float ex = expf(__uint_as_float(rec[j].x) - m);
        denl += ex;
        rec[j].x = __float_as_uint(ex);
    }
    for (int idx = beg + STORE_CAP + ln; idx < end; idx += 16) {   // overflow (rare)
        int s = esrc[idx];
        float e = a_s[s] + ad;
        e = (e > 0.f) ? e : 0.2f * e;
        denl += expf(e - m);
    }
    float den = denl;
    #pragma unroll
    for (int off = 1; off < 16; off <<= 1) den += __shfl_xor(den, off, 16);
    float rden = 1.f / den;

    // ---- phase C: finalize packed records {pw, srow}; 2 pads {0, ZROW} ----
    for (int j = ln; j < stored; j += 16) {
        uint2 r = rec[j];
        uint2 q;
        q.x = (uint)f2b(__uint_as_float(r.x) * rden) | (r.y & 0xffff0000u);
        q.y = r.y & 0xffffu;
        rec[j] = q;
    }
    if (ln < 2) { uint2 q; q.x = 0u; q.y = (uint)ZROW; rec[stored + ln] = q; }

    // ---- phase D: hot accumulate (1 edge/quad-pass, dual-body pipeline) ----
    float tg[8] = {}, tc[8] = {}, ts[8] = {};
    const ushort* xbs = xb + ln * 8;
    auto ldx = [&](uint srow) -> u8v {
        return *(const u8v*)(xbs + (size_t)srow * 128);
    };
    auto fmacc = [&](u8v x8, uint pw) {
        float wg = __uint_as_float(pw << 16);          // bf16 low  -> f32
        float wc = __uint_as_float(pw & 0xffff0000u);  // bf16 high -> f32
        #pragma unroll
        for (int k = 0; k < 8; ++k) {
            float xv = b2f(x8[k]);
            tg[k] += wg * xv;
            tc[k] += wc * xv;
            ts[k] += xv;                               // pads: x = 0 (ZROW)
        }
    };

    int Pcnt = (stored + 1) & ~1;        // even, >= 2 (self-loop => cnt >= 1)
    uint2 rA = rec[0]; u8v xA = ldx(rA.y);
    uint2 rB; u8v xB;
    int j = 0;
    for (;;) {
        rB = rec[j + 1]; xB = ldx(rB.y); // prefetch (pads: safe)
        fmacc(xA, rA.x);
        if (++j >= Pcnt) break;
        rA = rec[j + 1]; xA = ldx(rA.y);
        fmacc(xB, rB.x);
        if (++j >= Pcnt) break;
    }

    // ---- overflow accumulate (never taken for this input) ----
    for (int base = beg + STORE_CAP; base < end; base += 16) {
        int idx = base + ln;
        int s = ZROW; uint pw = 0;
        if (idx < end) {
            int ss = esrc[idx];
            float e = a_s[ss] + ad;
            e = (e > 0.f) ? e : 0.2f * e;
            pw = (uint)f2b(expf(e - m) * rden) | ((uint)f2b(dinv[ss] * dd) << 16);
            s = ss;
        }
        int cb = end - base; if (cb > 16) cb = 16;
        for (int jj = 0; jj < cb; ++jj) {
            int sa = __shfl(s, jj, 16);
            uint pa = (uint)__shfl((int)pw, jj, 16);
            fmacc(ldx((uint)sa), pa);
        }
    }

    // ---- epilogue: 16 lanes cover all 128 cols, 16B stores ----
    u8v xd = *(const u8v*)(xb + (size_t)d * 128 + ln * 8);
    int cs = cnt - 1;
    float rc = 1.f / (float)(cs > 1 ? cs : 1);
    u8v og, oc, os;
    #pragma unroll
    for (int k = 0; k < 8; ++k) {
        og[k] = f2b(tg[k]);
        oc[k] = f2b(tc[k]);
        os[k] = f2b((ts[k] - b2f(xd[k])) * rc);
    }
    size_t row = (size_t)d * 128 + ln * 8;
    *(u8v*)(tgb + row) = og;
    *(u8v*)(tcb + row) = oc;
    *(u8v*)(tsb + row) = os;
}

// ---------- merged producer GEMMs: z=0 GAT, z=1 GCN, z=2 SAGE ----------
__global__ __launch_bounds__(256, 3) void k_gemm_prod(
    const ushort* __restrict__ tgb, const ushort* __restrict__ tcb,
    const ushort* __restrict__ tsb, const ushort* __restrict__ xb,
    const ushort* __restrict__ btg, const ushort* __restrict__ btc,
    const ushort* __restrict__ btsg,
    const float* __restrict__ bg, const float* __restrict__ bc,
    const float* __restrict__ bsl,
    float* __restrict__ pS, float* __restrict__ pQ,   // [NBLK][C3] partials
    ushort* __restrict__ hch)
{
    constexpr int COLS = 128;
    constexpr int HOPU = 8 * COLS;               // 1024 units per half
    __shared__ __align__(16) ushort S[16384];    // 32 KB union
    ushort* Bs = S;
    ushort* As = S + 8192;
    float* red = (float*)(S + 14336);            // 256 floats (dead As region)

    const int z = blockIdx.z;
    const ushort* A1 = (z == 0) ? tgb : (z == 1) ? tcb : tsb;
    const ushort* Bt = (z == 0) ? btg : (z == 1) ? btc : btsg;
    const float*  bias = (z == 0) ? bg : (z == 1) ? bc : bsl;
    const int nch = (z == 2) ? 2 : 1;
    const int ktot = nch * 128;

    const int lane = threadIdx.x & 63;
    const int wave = threadIdx.x >> 6;
    const int quad = lane >> 4;
    const int ln15 = lane & 15;
    const int row0 = blockIdx.x * 128 + wave * 32;
    const int Rbase = blockIdx.x * 128;

    auto stageB = [&](int c, int h) {
        for (int u0 = wave * 64; u0 < HOPU; u0 += 256) {
            int u  = u0 + lane;
            int kq  = u / COLS;
            int col = u - kq * COLS;
            int kk  = c * 128 + h * 64 + kq * 8;
            const ushort* gp = Bt + (size_t)col * ktot + kk;
            async_copy16(gp, (char*)Bs + (size_t)u0 * 16);
        }
    };
    auto stageA = [&](int c, int h) {
        #pragma unroll
        for (int i = 0; i < 4; ++i) {
            int u0 = (wave * 4 + i) * 64;
            int u  = u0 + lane;
            int row = u >> 3;
            int s   = u & 7;
            int sg  = s ^ (row & 7);
            int rr = Rbase + row; if (rr > NN - 1) rr = NN - 1;
            int kk = c * 128 + h * 64 + sg * 8;
            const ushort* gp = (kk < 128) ? (A1 + (size_t)rr * 128 + kk)
                                          : (xb + (size_t)rr * 128 + (kk - 128));
            async_copy16(gp, (char*)As + (size_t)u0 * 16);
        }
    };
    auto afrag = [&](int jj, int mt) -> s8v {
        int r = wave * 32 + mt * 16 + ln15;
        int sg = jj * 4 + quad;
        int unit = r * 8 + (sg ^ (r & 7));
        return *(const s8v*)(As + (size_t)unit * 8);
    };

    f4v acc[2][8] = {};

    auto compute = [&](int jj) {
        s8v a0 = afrag(jj, 0);
        s8v a1 = afrag(jj, 1);
        #pragma unroll
        for (int t = 0; t < 8; ++t) {
            int ub = (jj * 4 + quad) * COLS + t * 16 + ln15;
            s8v b = *(const s8v*)(Bs + (size_t)ub * 8);
            acc[0][t] = __builtin_amdgcn_mfma_f32_16x16x32_bf16(a0, b, acc[0][t], 0, 0, 0);
            acc[1][t] = __builtin_amdgcn_mfma_f32_16x16x32_bf16(a1, b, acc[1][t], 0, 0, 0);
        }
    };

    stageB(0, 0); stageA(0, 0);
    __syncthreads();

    for (int ph = 0; ph < nch; ++ph) {
        for (int h = 0; h < 2; ++h) {
            compute(0); compute(1);
            if (!(ph == nch - 1 && h == 1)) {
                __syncthreads();
                int nc = ph, nh = h + 1;
                if (nh == 2) { nh = 0; ++nc; }
                stageB(nc, nh); stageA(nc, nh);
                __syncthreads();
            }
        }
    }

    // LDS-transpose epilogue + per-lane BN partials
    __syncthreads();
    if (threadIdx.x < 256) red[threadIdx.x] = 0.f;   // As dead; red disjoint from Lp
    ushort* Lp = S + wave * 2176;
    float sp[8] = {}, qp[8] = {};
    #pragma unroll
    for (int mt = 0; mt < 2; ++mt) {
        #pragma unroll
        for (int t = 0; t < 8; ++t) {
            #pragma unroll
            for (int r = 0; r < 4; ++r) {
                int rr = row0 + mt * 16 + quad * 4 + r;
                float v = acc[mt][t][r] + bias[t * 16 + ln15];
                Lp[(quad * 4 + r) * LDSW + t * 16 + ln15] = f2b(v);
                if (rr < NN) { sp[t] += v; qp[t] += v * v; }
            }
        }
        int cb = (lane & 31) * 4;
        #pragma unroll
        for (int it = 0; it < 8; ++it) {
            int row2 = it * 2 + (lane >> 5);
            int rr = row0 + mt * 16 + row2;
            uint2 v = *(uint2*)(Lp + row2 * LDSW + cb);
            if (rr < NN)
                *(uint2*)(hch + (size_t)rr * C3 + z * 128 + cb) = v;
        }
    }
    // cross-wave LDS reduce (no contended global atomics)
    __syncthreads();
    #pragma unroll
    for (int t = 0; t < 8; ++t) {
        float s = sp[t], q = qp[t];
        s += __shfl_xor(s, 16); s += __shfl_xor(s, 32);
        q += __shfl_xor(q, 16); q += __shfl_xor(q, 32);
        if (quad == 0) {
            atomicAdd(&red[t * 16 + ln15], s);          // LDS atomic
            atomicAdd(&red[128 + t * 16 + ln15], q);
        }
    }
    __syncthreads();
    if (threadIdx.x < 128) {
        size_t o = (size_t)blockIdx.x * C3 + z * 128 + threadIdx.x;
        pS[o] = red[threadIdx.x];
        pQ[o] = red[128 + threadIdx.x];
    }
}

// ---------- BN final: 4 threads/column over the 391-row partials ----------
__global__ void k_bn_final(const float* __restrict__ pS, const float* __restrict__ pQ,
                           const float* __restrict__ gamma, const float* __restrict__ beta,
                           float* __restrict__ scale, float* __restrict__ shift)
{
    int t = threadIdx.x;
    int j = blockIdx.x * 64 + (t >> 2);
    int part = t & 3;
    if (j >= C3) return;
    float s = 0.f, q = 0.f;
    for (int r = part; r < NBLK; r += 4) {
        s += pS[(size_t)r * C3 + j];
        q += pQ[(size_t)r * C3 + j];
    }
    s += __shfl_down(s, 2); s += __shfl_down(s, 1);
    q += __shfl_down(q, 2); q += __shfl_down(q, 1);
    if (part == 0) {
        const float rn = 1.f / (float)NN;
        float mu  = s * rn;
        float var = q * rn - mu * mu;
        float sc  = gamma[j] * rsqrtf(var + 1e-5f);
        scale[j] = sc;
        shift[j] = beta[j] - mu * sc;
    }
}

// ---------- MLP L1: one block per 128 rows, BOTH col-halves ----------
// hch chunk staged ONCE (async DMA), BN+relu applied in-place per chunk
// (each element BN'd exactly once, same op sequence as before -> bit-identical
// a1), then MFMAs for both column halves read the shared BN'd tile.
// vs old 2-col-block grid: halves hch fetch (76.8->38.4 MB) and BN VALU.
__global__ __launch_bounds__(256, 2) void k_gemm1(
    const ushort* __restrict__ A,        // hch [NN][384]
    const ushort* __restrict__ Bt,       // bt1 [256][384]
    const float* __restrict__ bias,      // b1 [256]
    ushort* __restrict__ Ch,             // a1 [NN][256]
    const float* __restrict__ bnscale, const float* __restrict__ bnshift)
{
    __shared__ __align__(16) ushort S[24576];   // 48 KB: Bs[16384] + As[8192]
    __shared__ float bns[768];                  // scale[384] + shift[384]
    ushort* Bs = S;
    ushort* As = S + 16384;

    const int lane = threadIdx.x & 63;
    const int wave = threadIdx.x >> 6;
    const int quad = lane >> 4;
    const int ln15 = lane & 15;
    const int Rbase = blockIdx.x * 128;
    const int row0 = Rbase + wave * 32;

    auto stageB = [&](int c, int h) {
        for (int u0 = wave * 64; u0 < 2048; u0 += 256) {
            int u   = u0 + lane;
            int chh = u >> 10;               // col-half
            int rem = u & 1023;
            int kq  = rem >> 7;
            int col = rem & 127;
            int kk  = c * 128 + h * 64 + kq * 8;
            async_copy16(Bt + (size_t)(chh * 128 + col) * 384 + kk,
                         (char*)Bs + (size_t)u0 * 16);
        }
    };
    auto stageA = [&](int c, int h) {
        #pragma unroll
        for (int i = 0; i < 4; ++i) {
            int u0 = (wave * 4 + i) * 64;
            int u  = u0 + lane;
            int row = u >> 3;
            int s   = u & 7;
            int sg  = s ^ (row & 7);
            int rr = Rbase + row; if (rr > NN - 1) rr = NN - 1;
            int kk = c * 128 + h * 64 + sg * 8;
            async_copy16(A + (size_t)rr * 384 + kk, (char*)As + (size_t)u0 * 16);
        }
    };
    auto afrag = [&](int jj, int mt) -> s8v {
        int r = wave * 32 + mt * 16 + ln15;
        int sg = jj * 4 + quad;
        int unit = r * 8 + (sg ^ (r & 7));
        return *(const s8v*)(As + (size_t)unit * 8);
    };
    // in-place BN+relu of the staged chunk (1024 units, 4/thread)
    auto bnpass = [&](int kk0) {
        #pragma unroll
        for (int i = 0; i < 4; ++i) {
            int u = threadIdx.x + i * 256;
            int sg = (u & 7) ^ ((u >> 3) & 7);
            int c0 = kk0 + sg * 8;
            u8v x8 = *(u8v*)(As + (size_t)u * 8);
            #pragma unroll
            for (int e = 0; e < 8; ++e) {
                float v = b2f(x8[e]) * bns[c0 + e] + bns[384 + c0 + e];
                v = v > 0.f ? v : 0.f;
                x8[e] = f2b(v);
            }
            *(u8v*)(As + (size_t)u * 8) = x8;
        }
    };

    f4v acc[2][2][8] = {};
    auto compute = [&](int jj) {
        s8v a0 = afrag(jj, 0);
        s8v a1 = afrag(jj, 1);
        #pragma unroll
        for (int chh = 0; chh < 2; ++chh) {
            #pragma unroll
            for (int t = 0; t < 8; ++t) {
                int ub = chh * 1024 + (jj * 4 + quad) * 128 + t * 16 + ln15;
                s8v b = *(const s8v*)(Bs + (size_t)ub * 8);
                acc[chh][0][t] = __builtin_amdgcn_mfma_f32_16x16x32_bf16(a0, b, acc[chh][0][t], 0, 0, 0);
                acc[chh][1][t] = __builtin_amdgcn_mfma_f32_16x16x32_bf16(a1, b, acc[chh][1][t], 0, 0, 0);
            }
        }
    };

    for (int j = threadIdx.x; j < 384; j += 256) {
        bns[j] = bnscale[j];
        bns[384 + j] = bnshift[j];
    }
    stageB(0, 0); stageA(0, 0);
    __syncthreads();

    #pragma unroll
    for (int ph = 0; ph < 3; ++ph) {
        #pragma unroll
        for (int h = 0; h < 2; ++h) {
            bnpass(ph * 128 + h * 64);
            __syncthreads();             // BN'd tile visible to all waves
            compute(0); compute(1);
            if (!(ph == 2 && h == 1)) {
                __syncthreads();
                int nc = ph, nh = h + 1;
                if (nh == 2) { nh = 0; ++nc; }
                stageB(nc, nh); stageA(nc, nh);
                __syncthreads();
            }
        }
    }

    // epilogue: relu(acc+bias) -> bf16 a1, both col halves (Bs region dead)
    __syncthreads();
    ushort* Lp = S + wave * 2176;
    #pragma unroll
    for (int chh = 0; chh < 2; ++chh) {
        int col0 = chh * 128;
        #pragma unroll
        for (int mt = 0; mt < 2; ++mt) {
            #pragma unroll
            for (int t = 0; t < 8; ++t) {
                int cc = col0 + t * 16 + ln15;
                #pragma unroll
                for (int r = 0; r < 4; ++r) {
                    float v = acc[chh][mt][t][r] + bias[cc];
                    v = v > 0.f ? v : 0.f;
                    Lp[(quad * 4 + r) * LDSW + t * 16 + ln15] = f2b(v);
                }
            }
            int cb = (lane & 31) * 4;
            #pragma unroll
            for (int it = 0; it < 8; ++it) {
                int row2 = it * 2 + (lane >> 5);
                int rr = row0 + mt * 16 + row2;
                uint2 v = *(uint2*)(Lp + row2 * LDSW + cb);
                if (rr < NN)
                    *(uint2*)(Ch + (size_t)rr * 256 + col0 + cb) = v;
            }
        }
    }
}

// ---------- fused MLP L2+L3: a2 stays in LDS, out fp32 ----------
__global__ __launch_bounds__(256, 2) void k_gemm23(
    const ushort* __restrict__ A,
    const ushort* __restrict__ Bt2, const ushort* __restrict__ Bt3,
    const float* __restrict__ b2v, const float* __restrict__ b3v,
    float* __restrict__ out)
{
    constexpr int COLS = 128;
    constexpr int HOPU = 1024;
    constexpr int KTOT = 256;
    __shared__ __align__(16) ushort S[16384];       // 32 KB staging; bt3 after
    __shared__ __align__(16) ushort A2[128 * A2W];  // 34 KB a2 bf16
    ushort* Bs = S;
    ushort* As = S + 8192;

    const int lane = threadIdx.x & 63;
    const int wave = threadIdx.x >> 6;
    const int quad = lane >> 4;
    const int ln15 = lane & 15;
    const int Rbase = blockIdx.x * 128;
    const int row0 = Rbase + wave * 32;

    auto stageB = [&](int c, int h) {
        for (int u0 = wave * 64; u0 < HOPU; u0 += 256) {
            int u  = u0 + lane;
            int kq  = u / COLS;
            int col = u - kq * COLS;
            int kk  = c * 128 + h * 64 + kq * 8;
            async_copy16(Bt2 + (size_t)col * KTOT + kk, (char*)Bs + (size_t)u0 * 16);
        }
    };
    auto stageA = [&](int c, int h) {
        #pragma unroll
        for (int i = 0; i < 4; ++i) {
            int u0 = (wave * 4 + i) * 64;
            int u  = u0 + lane;
            int row = u >> 3;
            int s   = u & 7;
            int sg  = s ^ (row & 7);
            int rr = Rbase + row; if (rr > NN - 1) rr = NN - 1;
            int kk = c * 128 + h * 64 + sg * 8;
            async_copy16(A + (size_t)rr * KTOT + kk, (char*)As + (size_t)u0 * 16);
        }
    };
    auto afrag = [&](int jj, int mt) -> s8v {
        int r = wave * 32 + mt * 16 + ln15;
        int sg = jj * 4 + quad;
        int unit = r * 8 + (sg ^ (r & 7));
        return *(const s8v*)(As + (size_t)unit * 8);
    };

    f4v acc[2][8] = {};
    auto compute = [&](int jj) {
        s8v a0 = afrag(jj, 0);
        s8v a1 = afrag(jj, 1);
        #pragma unroll
        for (int t = 0; t < 8; ++t) {
            int ub = (jj * 4 + quad) * COLS + t * 16 + ln15;
            s8v b = *(const s8v*)(Bs + (size_t)ub * 8);
            acc[0][t] = __builtin_amdgcn_mfma_f32_16x16x32_bf16(a0, b, acc[0][t], 0, 0, 0);
            acc[1][t] = __builtin_amdgcn_mfma_f32_16x16x32_bf16(a1, b, acc[1][t], 0, 0, 0);
        }
    };

    stageB(0, 0); stageA(0, 0);
    __syncthreads();
    #pragma unroll
    for (int ph = 0; ph < 2; ++ph) {
        #pragma unroll
        for (int h = 0; h < 2; ++h) {
            compute(0); compute(1);
            if (!(ph == 1 && h == 1)) {
                __syncthreads();
                int nc = ph, nh = h + 1;
                if (nh == 2) { nh = 0; ++nc; }
                stageB(nc, nh); stageA(nc, nh);
                __syncthreads();
            }
        }
    }

    __syncthreads();                     // staging dead; A2 not yet read
    // stage bt3 (48 cols x 128 k, both halves) into S — overlaps epilogue VALU
    for (int u0 = wave * 64; u0 < 768; u0 += 256) {
        int u = u0 + lane;
        int h = u / 384;
        int rem = u - h * 384;
        int kq = rem / 48;
        int col = rem - kq * 48;
        int kk = h * 64 + kq * 8;
        async_copy16(Bt3 + (size_t)col * 128 + kk, (char*)S + (size_t)u0 * 16);
    }
    // a2 = relu(acc + b2) -> LDS
    #pragma unroll
    for (int mt = 0; mt < 2; ++mt) {
        #pragma unroll
        for (int t = 0; t < 8; ++t) {
            int cc = t * 16 + ln15;
            float bb = b2v[cc];
            #pragma unroll
            for (int r = 0; r < 4; ++r) {
                int rl = wave * 32 + mt * 16 + quad * 4 + r;
                float v = acc[mt][t][r] + bb;
                v = v > 0.f ? v : 0.f;
                A2[(size_t)rl * A2W + cc] = f2b(v);
            }
        }
    }
    __syncthreads();                     // a2 written AND bt3 landed (vmcnt drain)

    // GEMM3: 128x40 = A2[128x128] @ bt3
    f4v acc3[2][3] = {};
    #pragma unroll
    for (int h = 0; h < 2; ++h) {
        #pragma unroll
        for (int jj = 0; jj < 2; ++jj) {
            int sg = jj * 4 + quad;
            int ko = h * 64 + sg * 8;
            s8v a0 = *(const s8v*)(A2 + (size_t)(wave * 32 + ln15) * A2W + ko);
            s8v a1 = *(const s8v*)(A2 + (size_t)(wave * 32 + 16 + ln15) * A2W + ko);
            #pragma unroll
            for (int t = 0; t < 3; ++t) {
                int ub = h * 384 + sg * 48 + t * 16 + ln15;
                s8v b = *(const s8v*)(S + (size_t)ub * 8);
                acc3[0][t] = __builtin_amdgcn_mfma_f32_16x16x32_bf16(a0, b, acc3[0][t], 0, 0, 0);
                acc3[1][t] = __builtin_amdgcn_mfma_f32_16x16x32_bf16(a1, b, acc3[1][t], 0, 0, 0);
            }
        }
    }
    #pragma unroll
    for (int t = 0; t < 3; ++t) {
        int cc = t * 16 + ln15;
        #pragma unroll
        for (int mt = 0; mt < 2; ++mt) {
            #pragma unroll
            for (int r = 0; r < 4; ++r) {
                int rr = row0 + mt * 16 + quad * 4 + r;
                if (rr < NN && cc < NOUT)
                    out[(size_t)rr * NOUT + cc] = acc3[mt][t][r] + b3v[cc];
            }
        }
    }
}

extern "C" void kernel_launch(void* const* d_in, const int* in_sizes, int n_in,
                              void* d_out, int out_size, void* d_ws, size_t ws_size,
                              hipStream_t stream) {
    const float* x        = (const float*)d_in[0];
    const int*   ei       = (const int*)d_in[1];
    const float* W_gat    = (const float*)d_in[2];
    const float* att_src  = (const float*)d_in[3];
    const float* att_dst  = (const float*)d_in[4];
    const float* b_gat    = (const float*)d_in[5];
    const float* W_gcn    = (const float*)d_in[6];
    const float* b_gcn    = (const float*)d_in[7];
    const float* W_sage_l = (const float*)d_in[8];
    const float* b_sage_l = (const float*)d_in[9];
    const float* W_sage_r = (const float*)d_in[10];
    const float* W1       = (const float*)d_in[11];
    const float* b1       = (const float*)d_in[12];
    const float* W2       = (const float*)d_in[13];
    const float* b2       = (const float*)d_in[14];
    const float* W3       = (const float*)d_in[15];
    const float* b3       = (const float*)d_in[16];
    const float* gamma    = (const float*)d_in[17];
    const float* beta     = (const float*)d_in[18];

    const int* e_src = ei;
    const int* e_dst = ei + EE;

    // ---- workspace layout (16B-aligned) ----
    char* base = (char*)d_ws;
    size_t o = 0;
    ushort* hch  = (ushort*)(base + o); o += (size_t)NN * C3 * 2;
    ushort* tgb  = (ushort*)(base + o); o += (size_t)NN * 128 * 2;    // a1 overlay
    ushort* tcb  = (ushort*)(base + o); o += (size_t)NN * 128 * 2;
    ushort* tsb  = (ushort*)(base + o); o += (size_t)NN * 128 * 2;
    ushort* xb   = (ushort*)(base + o); o += (size_t)(NN + 1) * 128 * 2;  // +ZROW
    ushort* esrc = (ushort*)(base + o); o += ((size_t)(EE + NN) * 2 + 15) & ~15ull;
    int*    offs = (int*)(base + o);    o += (size_t)(NN + 16) * 4;
    float*  as_  = (float*)(base + o);  o += (size_t)NN * 4;
    float*  ad_  = (float*)(base + o);  o += (size_t)NN * 4;
    float*  dinv = (float*)(base + o);  o += (size_t)NN * 4;
    // --- zero-init region: bcnt only ---
    int*    bcnt = (int*)(base + o);    o += 128 * 4;
    // --- end zero region ---
    float*  pS   = (float*)(base + o);  o += (size_t)NBLK * C3 * 4;   // written fully
    float*  pQ   = (float*)(base + o);  o += (size_t)NBLK * C3 * 4;
    float*  scale= (float*)(base + o);  o += C3 * 4;
    float*  shift= (float*)(base + o);  o += C3 * 4;
    float*  w_as = (float*)(base + o);  o += 128 * 4;
    float*  w_ad = (float*)(base + o);  o += 128 * 4;
    ushort* btg  = (ushort*)(base + o); o += 128 * 128 * 2;
    ushort* btc  = (ushort*)(base + o); o += 128 * 128 * 2;
    ushort* btsg = (ushort*)(base + o); o += 128 * 256 * 2;
    ushort* bt1  = (ushort*)(base + o); o += 256 * 384 * 2;
    ushort* bt2  = (ushort*)(base + o); o += 128 * 256 * 2;
    ushort* bt3  = (ushort*)(base + o); o += 48 * 128 * 2;
    // overlays (temporally disjoint)
    ushort* a1 = tgb;                        // NN*256 ushorts (tgb+tcb)
    uint*   ebuf = (uint*)hch;               // 6.4MB; hch first written by k_gemm_prod

    hipMemsetAsync(bcnt, 0, 128 * 4, stream);

    // 1. bucket sort + weight prep (merged)
    k_bucketw<<<BK_BLKS + 817, 1024, 0, stream>>>(
        e_src, e_dst, bcnt, ebuf,
        W_gat, W_gcn, W_sage_l, W_sage_r, W1, W2, W3,
        att_src, att_dst, w_as, w_ad, btg, btc, btsg, bt1, bt2, bt3);

    // 2. CSR build (deg+scan+scatter) + x split (merged)
    k_csrx<<<NBUCK + SXB, 1024, 0, stream>>>(
        bcnt, ebuf, offs, dinv, esrc,
        x, w_as, w_ad, xb, as_, ad_);

    // 3. gather (16-lane quads, 2-deep pipeline)
    k_gather<<<(NN + 15) / 16, 256, 0, stream>>>(
        esrc, offs, as_, ad_, dinv, xb, tgb, tcb, tsb);

    // 4. producers: one launch, privatized BN partials
    k_gemm_prod<<<dim3(NBLK, 1, 3), 256, 0, stream>>>(
        tgb, tcb, tsb, xb, btg, btc, btsg,
        b_gat, b_gcn, b_sage_l, pS, pQ, hch);

    // 5. BN fold (4 threads/col partials reduce)
    k_bn_final<<<6, 256, 0, stream>>>(pS, pQ, gamma, beta, scale, shift);

    // 6. MLP L1: single-pass BN, both col-halves per block
    k_gemm1<<<NBLK, 256, 0, stream>>>(hch, bt1, b1, a1, scale, shift);

    // 7. MLP L2+L3 fused (a2 in LDS, fp32 out)
    k_gemm23<<<NBLK, 256, 0, stream>>>(a1, bt2, bt3, b2, b3, (float*)d_out);
}

// Round 9
// 270.805 us; speedup vs baseline: 1.0212x; 1.0212x over previous
//
#include <hip/hip_runtime.h>
#include <cstdint>
#include <cstddef>

#define NN   50000
#define FIN  128
#define HD   128
#define EE   800000
#define C3   384   // 3*H
#define NOUT 40

#define NBLK ((NN + 127) / 128)                     // 391 row-blocks

#define NBUCK ((NN + 511) / 512)                    // 98 coarse dst-buckets
#define BCAP  16384                                 // per-bucket ebuf capacity
#define BK_BLKS ((EE + 8191) / 8192)                // 98 bucketing blocks
#define SCAP  12288                                 // csr staging (max ~9.2k)
#define SXB   ((NN + 16) / 16)                      // 3126 split_x blocks (16 nodes, incl ZROW)

#define RCAP      132                               // per-dst record slots (LDS)
#define STORE_CAP 128                               // fast-path record cap
#define ZROW NN                                     // zeroed xb row for pad records

#define LDSW 132   // padded epilogue LDS row stride (ushorts)
#define A2W  136   // gemm23 a2 LDS row stride (16B-aligned rows, 2-way banks)

typedef __attribute__((ext_vector_type(8))) short s8v;   // 8 x bf16 (4 VGPR)
typedef __attribute__((ext_vector_type(4))) float f4v;   // MFMA acc
typedef __attribute__((ext_vector_type(8))) ushort u8v;  // 8 x bf16 (16B)

typedef const __attribute__((address_space(1))) unsigned int* guintp;
typedef __attribute__((address_space(3))) unsigned int* luintp;

static __device__ __forceinline__ void async_copy16(const void* g, void* l) {
    __builtin_amdgcn_global_load_lds((guintp)g, (luintp)l, 16, 0, 0);
}

// ---------- bf16 helpers ----------
static __device__ __forceinline__ float b2f(ushort u) {
    return __uint_as_float((unsigned)u << 16);
}
static __device__ __forceinline__ ushort f2b(float v) {
    unsigned u = __float_as_uint(v);
    unsigned r = u + 0x7fffu + ((u >> 16) & 1u);
    return (ushort)(r >> 16);
}

// ---------- merged: edge bucket sort + weight transposes + att fold ----------
// blocks [0,98): bucket sort; blocks [98,915): weight prep (independent work).
__global__ __launch_bounds__(1024) void k_bucketw(
    const int* __restrict__ e_src, const int* __restrict__ e_dst,
    int* __restrict__ bcnt, uint* __restrict__ ebuf,
    const float* __restrict__ Wg, const float* __restrict__ Wc,
    const float* __restrict__ Wl, const float* __restrict__ Wr,
    const float* __restrict__ W1, const float* __restrict__ W2,
    const float* __restrict__ W3,
    const float* __restrict__ asv, const float* __restrict__ adv,
    float* __restrict__ w_as, float* __restrict__ w_ad,
    ushort* __restrict__ btg, ushort* __restrict__ btc,
    ushort* __restrict__ btsg,
    ushort* __restrict__ bt1, ushort* __restrict__ bt2,
    ushort* __restrict__ bt3)
{
    int t = threadIdx.x;
    if (blockIdx.x >= BK_BLKS) {
        int ry = blockIdx.x - BK_BLKS;
        if (ry == 816) {
            if (t < 128) {
                float s1 = 0.f, s2 = 0.f;
                for (int j = 0; j < 128; ++j) {
                    float w = Wg[t * 128 + j];
                    s1 += w * asv[j];
                    s2 += w * adv[j];
                }
                w_as[t] = s1; w_ad[t] = s2;
            }
            return;
        }
        const float* W = nullptr; ushort* dh; int K, Nw, n;
        bool sage = false;
        if (ry < 128)      { n = ry;       K = 128; Nw = 128; W = Wg; dh = btg; }
        else if (ry < 256) { n = ry - 128; K = 128; Nw = 128; W = Wc; dh = btc; }
        else if (ry < 384) { n = ry - 256; K = 256; Nw = 128; sage = true; dh = btsg; }
        else if (ry < 640) { n = ry - 384; K = 384; Nw = 256; W = W1; dh = bt1; }
        else if (ry < 768) { n = ry - 640; K = 256; Nw = 128; W = W2; dh = bt2; }
        else               { n = ry - 768; K = 128; Nw = 40;  W = W3; dh = bt3; }
        for (int k = t; k < K; k += 1024) {
            float v;
            if (sage) v = (k < 128) ? Wl[(size_t)k * 128 + n] : Wr[(size_t)(k - 128) * 128 + n];
            else      v = (n < Nw) ? W[(size_t)k * Nw + n] : 0.f;
            dh[(size_t)n * K + k] = f2b(v);
        }
        return;
    }
    __shared__ uint sval[8192];          // 32 KB staged packed edges
    __shared__ int scnt[NBUCK], sbase[NBUCK];
    if (t < NBUCK) scnt[t] = 0;
    __syncthreads();
    int e0 = blockIdx.x * 8192;
    #pragma unroll
    for (int i = 0; i < 8; ++i) {
        int g = e0 + i * 1024 + t;
        uint val = 0xffffffffu;          // sentinel (bucket 127 >= NBUCK)
        if (g < EE) {
            int d = e_dst[g];
            int s = e_src[g];
            int b = d >> 9;
            val = ((uint)b << 25) | ((uint)(d & 511) << 16) | (uint)s;
            atomicAdd(&scnt[b], 1);
        }
        sval[i * 1024 + t] = val;
    }
    __syncthreads();
    if (t < NBUCK) {
        sbase[t] = atomicAdd(&bcnt[t], scnt[t]);   // reserve contiguous run
        scnt[t] = 0;                                // reuse as local cursor
    }
    __syncthreads();
    #pragma unroll
    for (int i = 0; i < 8; ++i) {
        uint val = sval[i * 1024 + t];
        if (val != 0xffffffffu) {
            int b = val >> 25;
            int lo = atomicAdd(&scnt[b], 1);
            ebuf[(size_t)b * BCAP + sbase[b] + lo] = val;
        }
    }
}

// ---------- merged: (deg-hist + scan + in-LDS CSR scatter) AND x-split ----------
__global__ __launch_bounds__(1024) void k_csrx(
    const int* __restrict__ bcnt, const uint* __restrict__ ebuf,
    int* __restrict__ offs, float* __restrict__ dinv,
    ushort* __restrict__ esrc,
    const float* __restrict__ x,
    const float* __restrict__ w_as, const float* __restrict__ w_ad,
    ushort* __restrict__ xb, float* __restrict__ a_s, float* __restrict__ a_d)
{
    int t = threadIdx.x;
    if (blockIdx.x >= NBUCK) {
        int node = (blockIdx.x - NBUCK) * 16 + (t >> 6);
        if (node > NN) return;
        int lane = t & 63;
        size_t o = (size_t)node * 128 + lane * 2;
        if (node == NN) {                // ZROW: all-zero pad row
            ushort2 z; z.x = 0; z.y = 0;
            *(ushort2*)(xb + o) = z;
            return;
        }
        float2 v  = *(const float2*)(x + o);
        { ushort2 u; u.x = f2b(v.x); u.y = f2b(v.y); *(ushort2*)(xb + o) = u; }
        float2 w1 = *(const float2*)(w_as + lane * 2);
        float2 w2 = *(const float2*)(w_ad + lane * 2);
        float s1 = v.x * w1.x + v.y * w1.y;
        float s2 = v.x * w2.x + v.y * w2.y;
        #pragma unroll
        for (int off = 32; off; off >>= 1) {
            s1 += __shfl_down(s1, off);
            s2 += __shfl_down(s2, off);
        }
        if (lane == 0) { a_s[node] = s1; a_d[node] = s2; }
        return;
    }
    __shared__ ushort sout[SCAP];        // 24 KB staging
    __shared__ int hist[512];            // degree hist, reused as cursors
    __shared__ int sh[256];
    __shared__ int btop_s;
    int b = blockIdx.x;
    int d0 = b * 512;
    int ndst = NN - d0; if (ndst > 512) ndst = 512;
    if (t < 512) hist[t] = 0;
    __syncthreads();
    int nb = bcnt[b];
    const uint* eb = ebuf + (size_t)b * BCAP;
    for (int i = t; i < nb; i += 1024)
        atomicAdd(&hist[(eb[i] >> 16) & 511], 1);
    __syncthreads();
    if (t < 64) {                        // top-level exclusive prefix for bucket b
        int acc = 0;
        for (int i = t; i < b; i += 64) {
            int nd = NN - i * 512; if (nd > 512) nd = 512;
            acc += bcnt[i] + nd;
        }
        #pragma unroll
        for (int off = 32; off; off >>= 1) acc += __shfl_down(acc, off);
        if (t == 0) btop_s = acc;
    }
    int v0 = 0, v1 = 0;
    if (t < 256) {
        int i0g = d0 + t * 2;
        v0 = (i0g < NN) ? hist[t * 2] + 1 : 0;
        v1 = (i0g + 1 < NN) ? hist[t * 2 + 1] + 1 : 0;
        sh[t] = v0 + v1;
    }
    __syncthreads();
    for (int off = 1; off < 256; off <<= 1) {
        int u = 0;
        if (t < 256 && t >= off) u = sh[t - off];
        __syncthreads();
        if (t < 256) sh[t] += u;
        __syncthreads();
    }
    if (t < 256) {
        int pair = v0 + v1;
        int lex = sh[t] - pair;          // bucket-local exclusive
        int excl = lex + btop_s;
        int i0g = d0 + t * 2;
        if (i0g < NN) {
            offs[i0g] = excl; dinv[i0g] = rsqrtf((float)v0);
            hist[t * 2] = lex;           // cursor (hist value consumed above)
        }
        if (i0g + 1 < NN) {
            offs[i0g + 1] = excl + v0; dinv[i0g + 1] = rsqrtf((float)v1);
            hist[t * 2 + 1] = lex + v0;
        }
        if (b == NBUCK - 1 && t == 255) offs[NN] = excl + pair;
    }
    __syncthreads();
    for (int i = t; i < nb; i += 1024) {
        uint val = eb[i];
        int slot = atomicAdd(&hist[(val >> 16) & 511], 1);
        sout[slot] = (ushort)(val & 0xffffu);
    }
    if (t < ndst) {                      // self loops
        int slot = atomicAdd(&hist[t], 1);
        sout[slot] = (ushort)(d0 + t);
    }
    __syncthreads();
    int total = nb + ndst;
    int obase = btop_s;
    for (int i = t; i < total; i += 1024)
        esrc[obase + i] = sout[i];       // contiguous full-line writes
}

// ---------- CSR gather: 16-lane quads, 2-deep dual-body (no spill) ----------
__global__ __launch_bounds__(256) void k_gather(
    const ushort* __restrict__ esrc, const int* __restrict__ offs,
    const float* __restrict__ a_s, const float* __restrict__ a_d,
    const float* __restrict__ dinv,
    const ushort* __restrict__ xb,
    ushort* __restrict__ tgb, ushort* __restrict__ tcb,
    ushort* __restrict__ tsb)
{
    __shared__ uint2 recs[16][RCAP];     // 16.5 KB: per-quad edge records
    int t = threadIdx.x;
    int qid = t >> 4;
    int ln = t & 15;
    int d = blockIdx.x * 16 + qid;
    if (d >= NN) return;
    uint2* rec = recs[qid];
    int beg = offs[d], end = offs[d + 1];
    int cnt = end - beg;
    float ad = a_d[d], dd = dinv[d];
    int stored = cnt < STORE_CAP ? cnt : STORE_CAP;

    // ---- phase A: e + wc into records, track max ----
    float mloc = -3.0e38f;
    for (int b = 0; b < cnt; b += 16) {
        int j = b + ln;
        if (j < cnt) {
            int s = esrc[beg + j];
            float e = a_s[s] + ad;
            e = (e > 0.f) ? e : 0.2f * e;
            mloc = fmaxf(mloc, e);
            if (j < STORE_CAP) {
                uint2 r;
                r.x = __float_as_uint(e);
                r.y = (uint)s | ((uint)f2b(dinv[s] * dd) << 16);
                rec[j] = r;
            }
        }
    }
    float m = mloc;
    #pragma unroll
    for (int off = 1; off < 16; off <<= 1) m = fmaxf(m, __shfl_xor(m, off, 16));

    // ---- phase B: exp + denom ----
    float denl = 0.f;
    for (int j = ln; j < stored; j += 16) {
        float ex = expf(__uint_as_float(rec[j].x) - m);
        denl += ex;
        rec[j].x = __float_as_uint(ex);
    }
    for (int idx = beg + STORE_CAP + ln; idx < end; idx += 16) {   // overflow (rare)
        int s = esrc[idx];
        float e = a_s[s] + ad;
        e = (e > 0.f) ? e : 0.2f * e;
        denl += expf(e - m);
    }
    float den = denl;
    #pragma unroll
    for (int off = 1; off < 16; off <<= 1) den += __shfl_xor(den, off, 16);
    float rden = 1.f / den;

    // ---- phase C: finalize packed records {pw, srow}; 2 pads {0, ZROW} ----
    for (int j = ln; j < stored; j += 16) {
        uint2 r = rec[j];
        uint2 q;
        q.x = (uint)f2b(__uint_as_float(r.x) * rden) | (r.y & 0xffff0000u);
        q.y = r.y & 0xffffu;
        rec[j] = q;
    }
    if (ln < 2) { uint2 q; q.x = 0u; q.y = (uint)ZROW; rec[stored + ln] = q; }

    // ---- phase D: hot accumulate (1 edge/quad-pass, dual-body pipeline) ----
    float tg[8] = {}, tc[8] = {}, ts[8] = {};
    const ushort* xbs = xb + ln * 8;
    auto ldx = [&](uint srow) -> u8v {
        return *(const u8v*)(xbs + (size_t)srow * 128);
    };
    auto fmacc = [&](u8v x8, uint pw) {
        float wg = __uint_as_float(pw << 16);          // bf16 low  -> f32
        float wc = __uint_as_float(pw & 0xffff0000u);  // bf16 high -> f32
        #pragma unroll
        for (int k = 0; k < 8; ++k) {
            float xv = b2f(x8[k]);
            tg[k] += wg * xv;
            tc[k] += wc * xv;
            ts[k] += xv;                               // pads: x = 0 (ZROW)
        }
    };

    int Pcnt = (stored + 1) & ~1;        // even, >= 2 (self-loop => cnt >= 1)
    uint2 rA = rec[0]; u8v xA = ldx(rA.y);
    uint2 rB; u8v xB;
    int j = 0;
    for (;;) {
        rB = rec[j + 1]; xB = ldx(rB.y); // prefetch (pads: safe)
        fmacc(xA, rA.x);
        if (++j >= Pcnt) break;
        rA = rec[j + 1]; xA = ldx(rA.y);
        fmacc(xB, rB.x);
        if (++j >= Pcnt) break;
    }

    // ---- overflow accumulate (never taken for this input) ----
    for (int base = beg + STORE_CAP; base < end; base += 16) {
        int idx = base + ln;
        int s = ZROW; uint pw = 0;
        if (idx < end) {
            int ss = esrc[idx];
            float e = a_s[ss] + ad;
            e = (e > 0.f) ? e : 0.2f * e;
            pw = (uint)f2b(expf(e - m) * rden) | ((uint)f2b(dinv[ss] * dd) << 16);
            s = ss;
        }
        int cb = end - base; if (cb > 16) cb = 16;
        for (int jj = 0; jj < cb; ++jj) {
            int sa = __shfl(s, jj, 16);
            uint pa = (uint)__shfl((int)pw, jj, 16);
            fmacc(ldx((uint)sa), pa);
        }
    }

    // ---- epilogue: 16 lanes cover all 128 cols, 16B stores ----
    u8v xd = *(const u8v*)(xb + (size_t)d * 128 + ln * 8);
    int cs = cnt - 1;
    float rc = 1.f / (float)(cs > 1 ? cs : 1);
    u8v og, oc, os;
    #pragma unroll
    for (int k = 0; k < 8; ++k) {
        og[k] = f2b(tg[k]);
        oc[k] = f2b(tc[k]);
        os[k] = f2b((ts[k] - b2f(xd[k])) * rc);
    }
    size_t row = (size_t)d * 128 + ln * 8;
    *(u8v*)(tgb + row) = og;
    *(u8v*)(tcb + row) = oc;
    *(u8v*)(tsb + row) = os;
}

// ---------- merged producer GEMMs: z=0 GAT, z=1 GCN, z=2 SAGE ----------
__global__ __launch_bounds__(256, 3) void k_gemm_prod(
    const ushort* __restrict__ tgb, const ushort* __restrict__ tcb,
    const ushort* __restrict__ tsb, const ushort* __restrict__ xb,
    const ushort* __restrict__ btg, const ushort* __restrict__ btc,
    const ushort* __restrict__ btsg,
    const float* __restrict__ bg, const float* __restrict__ bc,
    const float* __restrict__ bsl,
    float* __restrict__ pS, float* __restrict__ pQ,   // [NBLK][C3] partials
    ushort* __restrict__ hch)
{
    constexpr int COLS = 128;
    constexpr int HOPU = 8 * COLS;               // 1024 units per half
    __shared__ __align__(16) ushort S[16384];    // 32 KB union
    ushort* Bs = S;
    ushort* As = S + 8192;
    float* red = (float*)(S + 14336);            // 256 floats (dead As region)

    const int z = blockIdx.z;
    const ushort* A1 = (z == 0) ? tgb : (z == 1) ? tcb : tsb;
    const ushort* Bt = (z == 0) ? btg : (z == 1) ? btc : btsg;
    const float*  bias = (z == 0) ? bg : (z == 1) ? bc : bsl;
    const int nch = (z == 2) ? 2 : 1;
    const int ktot = nch * 128;

    const int lane = threadIdx.x & 63;
    const int wave = threadIdx.x >> 6;
    const int quad = lane >> 4;
    const int ln15 = lane & 15;
    const int row0 = blockIdx.x * 128 + wave * 32;
    const int Rbase = blockIdx.x * 128;

    auto stageB = [&](int c, int h) {
        for (int u0 = wave * 64; u0 < HOPU; u0 += 256) {
            int u  = u0 + lane;
            int kq  = u / COLS;
            int col = u - kq * COLS;
            int kk  = c * 128 + h * 64 + kq * 8;
            const ushort* gp = Bt + (size_t)col * ktot + kk;
            async_copy16(gp, (char*)Bs + (size_t)u0 * 16);
        }
    };
    auto stageA = [&](int c, int h) {
        #pragma unroll
        for (int i = 0; i < 4; ++i) {
            int u0 = (wave * 4 + i) * 64;
            int u  = u0 + lane;
            int row = u >> 3;
            int s   = u & 7;
            int sg  = s ^ (row & 7);
            int rr = Rbase + row; if (rr > NN - 1) rr = NN - 1;
            int kk = c * 128 + h * 64 + sg * 8;
            const ushort* gp = (kk < 128) ? (A1 + (size_t)rr * 128 + kk)
                                          : (xb + (size_t)rr * 128 + (kk - 128));
            async_copy16(gp, (char*)As + (size_t)u0 * 16);
        }
    };
    auto afrag = [&](int jj, int mt) -> s8v {
        int r = wave * 32 + mt * 16 + ln15;
        int sg = jj * 4 + quad;
        int unit = r * 8 + (sg ^ (r & 7));
        return *(const s8v*)(As + (size_t)unit * 8);
    };

    f4v acc[2][8] = {};

    auto compute = [&](int jj) {
        s8v a0 = afrag(jj, 0);
        s8v a1 = afrag(jj, 1);
        #pragma unroll
        for (int t = 0; t < 8; ++t) {
            int ub = (jj * 4 + quad) * COLS + t * 16 + ln15;
            s8v b = *(const s8v*)(Bs + (size_t)ub * 8);
            acc[0][t] = __builtin_amdgcn_mfma_f32_16x16x32_bf16(a0, b, acc[0][t], 0, 0, 0);
            acc[1][t] = __builtin_amdgcn_mfma_f32_16x16x32_bf16(a1, b, acc[1][t], 0, 0, 0);
        }
    };

    stageB(0, 0); stageA(0, 0);
    __syncthreads();

    for (int ph = 0; ph < nch; ++ph) {
        for (int h = 0; h < 2; ++h) {
            compute(0); compute(1);
            if (!(ph == nch - 1 && h == 1)) {
                __syncthreads();
                int nc = ph, nh = h + 1;
                if (nh == 2) { nh = 0; ++nc; }
                stageB(nc, nh); stageA(nc, nh);
                __syncthreads();
            }
        }
    }

    // LDS-transpose epilogue + per-lane BN partials
    __syncthreads();
    if (threadIdx.x < 256) red[threadIdx.x] = 0.f;   // As dead; red disjoint from Lp
    ushort* Lp = S + wave * 2176;
    float sp[8] = {}, qp[8] = {};
    #pragma unroll
    for (int mt = 0; mt < 2; ++mt) {
        #pragma unroll
        for (int t = 0; t < 8; ++t) {
            #pragma unroll
            for (int r = 0; r < 4; ++r) {
                int rr = row0 + mt * 16 + quad * 4 + r;
                float v = acc[mt][t][r] + bias[t * 16 + ln15];
                Lp[(quad * 4 + r) * LDSW + t * 16 + ln15] = f2b(v);
                if (rr < NN) { sp[t] += v; qp[t] += v * v; }
            }
        }
        int cb = (lane & 31) * 4;
        #pragma unroll
        for (int it = 0; it < 8; ++it) {
            int row2 = it * 2 + (lane >> 5);
            int rr = row0 + mt * 16 + row2;
            uint2 v = *(uint2*)(Lp + row2 * LDSW + cb);
            if (rr < NN)
                *(uint2*)(hch + (size_t)rr * C3 + z * 128 + cb) = v;
        }
    }
    // cross-wave LDS reduce (no contended global atomics)
    __syncthreads();
    #pragma unroll
    for (int t = 0; t < 8; ++t) {
        float s = sp[t], q = qp[t];
        s += __shfl_xor(s, 16); s += __shfl_xor(s, 32);
        q += __shfl_xor(q, 16); q += __shfl_xor(q, 32);
        if (quad == 0) {
            atomicAdd(&red[t * 16 + ln15], s);          // LDS atomic
            atomicAdd(&red[128 + t * 16 + ln15], q);
        }
    }
    __syncthreads();
    if (threadIdx.x < 128) {
        size_t o = (size_t)blockIdx.x * C3 + z * 128 + threadIdx.x;
        pS[o] = red[threadIdx.x];
        pQ[o] = red[128 + threadIdx.x];
    }
}

// ---------- BN final: 4 threads/column over the 391-row partials ----------
__global__ void k_bn_final(const float* __restrict__ pS, const float* __restrict__ pQ,
                           const float* __restrict__ gamma, const float* __restrict__ beta,
                           float* __restrict__ scale, float* __restrict__ shift)
{
    int t = threadIdx.x;
    int j = blockIdx.x * 64 + (t >> 2);
    int part = t & 3;
    if (j >= C3) return;
    float s = 0.f, q = 0.f;
    for (int r = part; r < NBLK; r += 4) {
        s += pS[(size_t)r * C3 + j];
        q += pQ[(size_t)r * C3 + j];
    }
    s += __shfl_down(s, 2); s += __shfl_down(s, 1);
    q += __shfl_down(q, 2); q += __shfl_down(q, 1);
    if (part == 0) {
        const float rn = 1.f / (float)NN;
        float mu  = s * rn;
        float var = q * rn - mu * mu;
        float sc  = gamma[j] * rsqrtf(var + 1e-5f);
        scale[j] = sc;
        shift[j] = beta[j] - mu * sc;
    }
}

// ---------- MFMA GEMM (L1): BN+relu at afrag-read, async-DMA staging ----------
template<int NT, int NCH, int AX, int BN>
__global__ __launch_bounds__(256, BN ? 4 : 5) void k_gemm2(
    const ushort* __restrict__ A, int K,
    const ushort* __restrict__ Bt,
    int M, int mode,
    const float* __restrict__ bias,
    float* __restrict__ Cf, int ldc,
    ushort* __restrict__ Ch, int ldch,
    int colmax,
    const float* __restrict__ bnscale, const float* __restrict__ bnshift)
{
    constexpr int COLS = NT * 16;
    constexpr int HOPU = 8 * COLS;       // B 16B-units per 64-k half (1 plane)
    constexpr int KTOT = NCH * 128;

    __shared__ __align__(16) ushort S[16384];   // 32 KB union
    __shared__ float bns[BN ? 768 : 4];         // BN scale[384] + shift[384]
    ushort* Bs = S;
    ushort* As = S + 8192;

    const int lane = threadIdx.x & 63;
    const int wave = threadIdx.x >> 6;
    const int quad = lane >> 4;
    const int ln15 = lane & 15;
    const int brow = AX ? blockIdx.y : blockIdx.x;
    const int bcol = AX ? blockIdx.x : blockIdx.y;
    const int row0 = brow * 128 + wave * 32;
    const int col0 = bcol * COLS;
    const int Rbase = brow * 128;

    auto stageB = [&](int c, int h) {
        for (int u0 = wave * 64; u0 < HOPU; u0 += 256) {
            int u  = u0 + lane;
            int kq  = u / COLS;
            int col = u - kq * COLS;
            int kk  = c * 128 + h * 64 + kq * 8;
            const ushort* gp = Bt + (size_t)(col0 + col) * KTOT + kk;
            async_copy16(gp, (char*)Bs + (size_t)u0 * 16);
        }
    };
    auto stageA = [&](int c, int h) {
        #pragma unroll
        for (int i = 0; i < 4; ++i) {
            int u0 = (wave * 4 + i) * 64;
            int u  = u0 + lane;
            int row = u >> 3;
            int s   = u & 7;
            int sg  = s ^ (row & 7);
            int rr = Rbase + row; if (rr > M - 1) rr = M - 1;
            int kk = c * 128 + h * 64 + sg * 8;
            const ushort* gp = A + (size_t)rr * K + kk;
            async_copy16(gp, (char*)As + (size_t)u0 * 16);
        }
    };
    auto afrag = [&](int jj, int mt) -> s8v {
        int r = wave * 32 + mt * 16 + ln15;
        int sg = jj * 4 + quad;
        int unit = r * 8 + (sg ^ (r & 7));
        return *(const s8v*)(As + (size_t)unit * 8);
    };

    f4v acc[2][NT] = {};

    auto compute = [&](int jj, int kk0) {
        s8v a0 = afrag(jj, 0);
        s8v a1 = afrag(jj, 1);
        if constexpr (BN) {
            int cb0 = kk0 + (jj * 4 + quad) * 8;
            #pragma unroll
            for (int e = 0; e < 8; ++e) {
                float sc = bns[cb0 + e];
                float sh = bns[384 + cb0 + e];
                float v0 = b2f((ushort)a0[e]) * sc + sh;
                float v1 = b2f((ushort)a1[e]) * sc + sh;
                v0 = v0 > 0.f ? v0 : 0.f;
                v1 = v1 > 0.f ? v1 : 0.f;
                a0[e] = (short)f2b(v0);
                a1[e] = (short)f2b(v1);
            }
        }
        #pragma unroll
        for (int t = 0; t < NT; ++t) {
            int ub = (jj * 4 + quad) * COLS + t * 16 + ln15;
            s8v b = *(const s8v*)(Bs + (size_t)ub * 8);
            acc[0][t] = __builtin_amdgcn_mfma_f32_16x16x32_bf16(a0, b, acc[0][t], 0, 0, 0);
            acc[1][t] = __builtin_amdgcn_mfma_f32_16x16x32_bf16(a1, b, acc[1][t], 0, 0, 0);
        }
    };

    if constexpr (BN) {
        for (int j = threadIdx.x; j < 384; j += 256) {
            bns[j] = bnscale[j];
            bns[384 + j] = bnshift[j];
        }
    }
    stageB(0, 0); stageA(0, 0);
    __syncthreads();

    #pragma unroll
    for (int ph = 0; ph < NCH; ++ph) {
        #pragma unroll
        for (int h = 0; h < 2; ++h) {
            int kk0 = ph * 128 + h * 64;
            compute(0, kk0); compute(1, kk0);
            if (!(ph == NCH - 1 && h == 1)) {
                __syncthreads();
                int nc = ph, nh = h + 1;
                if (nh == 2) { nh = 0; ++nc; }
                stageB(nc, nh); stageA(nc, nh);
                __syncthreads();
            }
        }
    }

    if (NT == 8 && mode == 0) {
        __syncthreads();                          // staging LDS free now
        ushort* Lp = S + wave * 2176;             // wave-private quarter
        #pragma unroll
        for (int mt = 0; mt < 2; ++mt) {
            #pragma unroll
            for (int t = 0; t < NT; ++t) {
                int cc = col0 + t * 16 + ln15;
                #pragma unroll
                for (int r = 0; r < 4; ++r) {
                    float v = acc[mt][t][r] + bias[cc];
                    v = v > 0.f ? v : 0.f;
                    Lp[(quad * 4 + r) * LDSW + t * 16 + ln15] = f2b(v);
                }
            }
            int cb = (lane & 31) * 4;
            #pragma unroll
            for (int it = 0; it < 8; ++it) {
                int row2 = it * 2 + (lane >> 5);
                int rr = row0 + mt * 16 + row2;
                uint2 v = *(uint2*)(Lp + row2 * LDSW + cb);
                if (rr < M)
                    *(uint2*)(Ch + (size_t)rr * ldch + col0 + cb) = v;
            }
        }
    } else {
        #pragma unroll
        for (int t = 0; t < NT; ++t) {
            int cc = col0 + t * 16 + ln15;
            #pragma unroll
            for (int mt = 0; mt < 2; ++mt) {
                #pragma unroll
                for (int r = 0; r < 4; ++r) {
                    int rr = row0 + mt * 16 + quad * 4 + r;
                    if (rr < M && cc < colmax)
                        Cf[(size_t)rr * ldc + cc] = acc[mt][t][r] + bias[cc];
                }
            }
        }
    }
}

// ---------- fused MLP L2+L3: a2 stays in LDS, out fp32 ----------
__global__ __launch_bounds__(256, 2) void k_gemm23(
    const ushort* __restrict__ A,
    const ushort* __restrict__ Bt2, const ushort* __restrict__ Bt3,
    const float* __restrict__ b2v, const float* __restrict__ b3v,
    float* __restrict__ out)
{
    constexpr int COLS = 128;
    constexpr int HOPU = 1024;
    constexpr int KTOT = 256;
    __shared__ __align__(16) ushort S[16384];       // 32 KB staging; bt3 after
    __shared__ __align__(16) ushort A2[128 * A2W];  // 34 KB a2 bf16
    ushort* Bs = S;
    ushort* As = S + 8192;

    const int lane = threadIdx.x & 63;
    const int wave = threadIdx.x >> 6;
    const int quad = lane >> 4;
    const int ln15 = lane & 15;
    const int Rbase = blockIdx.x * 128;
    const int row0 = Rbase + wave * 32;

    auto stageB = [&](int c, int h) {
        for (int u0 = wave * 64; u0 < HOPU; u0 += 256) {
            int u  = u0 + lane;
            int kq  = u / COLS;
            int col = u - kq * COLS;
            int kk  = c * 128 + h * 64 + kq * 8;
            async_copy16(Bt2 + (size_t)col * KTOT + kk, (char*)Bs + (size_t)u0 * 16);
        }
    };
    auto stageA = [&](int c, int h) {
        #pragma unroll
        for (int i = 0; i < 4; ++i) {
            int u0 = (wave * 4 + i) * 64;
            int u  = u0 + lane;
            int row = u >> 3;
            int s   = u & 7;
            int sg  = s ^ (row & 7);
            int rr = Rbase + row; if (rr > NN - 1) rr = NN - 1;
            int kk = c * 128 + h * 64 + sg * 8;
            async_copy16(A + (size_t)rr * KTOT + kk, (char*)As + (size_t)u0 * 16);
        }
    };
    auto afrag = [&](int jj, int mt) -> s8v {
        int r = wave * 32 + mt * 16 + ln15;
        int sg = jj * 4 + quad;
        int unit = r * 8 + (sg ^ (r & 7));
        return *(const s8v*)(As + (size_t)unit * 8);
    };

    f4v acc[2][8] = {};
    auto compute = [&](int jj) {
        s8v a0 = afrag(jj, 0);
        s8v a1 = afrag(jj, 1);
        #pragma unroll
        for (int t = 0; t < 8; ++t) {
            int ub = (jj * 4 + quad) * COLS + t * 16 + ln15;
            s8v b = *(const s8v*)(Bs + (size_t)ub * 8);
            acc[0][t] = __builtin_amdgcn_mfma_f32_16x16x32_bf16(a0, b, acc[0][t], 0, 0, 0);
            acc[1][t] = __builtin_amdgcn_mfma_f32_16x16x32_bf16(a1, b, acc[1][t], 0, 0, 0);
        }
    };

    stageB(0, 0); stageA(0, 0);
    __syncthreads();
    #pragma unroll
    for (int ph = 0; ph < 2; ++ph) {
        #pragma unroll
        for (int h = 0; h < 2; ++h) {
            compute(0); compute(1);
            if (!(ph == 1 && h == 1)) {
                __syncthreads();
                int nc = ph, nh = h + 1;
                if (nh == 2) { nh = 0; ++nc; }
                stageB(nc, nh); stageA(nc, nh);
                __syncthreads();
            }
        }
    }

    __syncthreads();                     // staging dead; A2 not yet read
    // stage bt3 (48 cols x 128 k, both halves) into S — overlaps epilogue VALU
    for (int u0 = wave * 64; u0 < 768; u0 += 256) {
        int u = u0 + lane;
        int h = u / 384;
        int rem = u - h * 384;
        int kq = rem / 48;
        int col = rem - kq * 48;
        int kk = h * 64 + kq * 8;
        async_copy16(Bt3 + (size_t)col * 128 + kk, (char*)S + (size_t)u0 * 16);
    }
    // a2 = relu(acc + b2) -> LDS
    #pragma unroll
    for (int mt = 0; mt < 2; ++mt) {
        #pragma unroll
        for (int t = 0; t < 8; ++t) {
            int cc = t * 16 + ln15;
            float bb = b2v[cc];
            #pragma unroll
            for (int r = 0; r < 4; ++r) {
                int rl = wave * 32 + mt * 16 + quad * 4 + r;
                float v = acc[mt][t][r] + bb;
                v = v > 0.f ? v : 0.f;
                A2[(size_t)rl * A2W + cc] = f2b(v);
            }
        }
    }
    __syncthreads();                     // a2 written AND bt3 landed (vmcnt drain)

    // GEMM3: 128x40 = A2[128x128] @ bt3
    f4v acc3[2][3] = {};
    #pragma unroll
    for (int h = 0; h < 2; ++h) {
        #pragma unroll
        for (int jj = 0; jj < 2; ++jj) {
            int sg = jj * 4 + quad;
            int ko = h * 64 + sg * 8;
            s8v a0 = *(const s8v*)(A2 + (size_t)(wave * 32 + ln15) * A2W + ko);
            s8v a1 = *(const s8v*)(A2 + (size_t)(wave * 32 + 16 + ln15) * A2W + ko);
            #pragma unroll
            for (int t = 0; t < 3; ++t) {
                int ub = h * 384 + sg * 48 + t * 16 + ln15;
                s8v b = *(const s8v*)(S + (size_t)ub * 8);
                acc3[0][t] = __builtin_amdgcn_mfma_f32_16x16x32_bf16(a0, b, acc3[0][t], 0, 0, 0);
                acc3[1][t] = __builtin_amdgcn_mfma_f32_16x16x32_bf16(a1, b, acc3[1][t], 0, 0, 0);
            }
        }
    }
    #pragma unroll
    for (int t = 0; t < 3; ++t) {
        int cc = t * 16 + ln15;
        #pragma unroll
        for (int mt = 0; mt < 2; ++mt) {
            #pragma unroll
            for (int r = 0; r < 4; ++r) {
                int rr = row0 + mt * 16 + quad * 4 + r;
                if (rr < NN && cc < NOUT)
                    out[(size_t)rr * NOUT + cc] = acc3[mt][t][r] + b3v[cc];
            }
        }
    }
}

extern "C" void kernel_launch(void* const* d_in, const int* in_sizes, int n_in,
                              void* d_out, int out_size, void* d_ws, size_t ws_size,
                              hipStream_t stream) {
    const float* x        = (const float*)d_in[0];
    const int*   ei       = (const int*)d_in[1];
    const float* W_gat    = (const float*)d_in[2];
    const float* att_src  = (const float*)d_in[3];
    const float* att_dst  = (const float*)d_in[4];
    const float* b_gat    = (const float*)d_in[5];
    const float* W_gcn    = (const float*)d_in[6];
    const float* b_gcn    = (const float*)d_in[7];
    const float* W_sage_l = (const float*)d_in[8];
    const float* b_sage_l = (const float*)d_in[9];
    const float* W_sage_r = (const float*)d_in[10];
    const float* W1       = (const float*)d_in[11];
    const float* b1       = (const float*)d_in[12];
    const float* W2       = (const float*)d_in[13];
    const float* b2       = (const float*)d_in[14];
    const float* W3       = (const float*)d_in[15];
    const float* b3       = (const float*)d_in[16];
    const float* gamma    = (const float*)d_in[17];
    const float* beta     = (const float*)d_in[18];

    const int* e_src = ei;
    const int* e_dst = ei + EE;

    // ---- workspace layout (16B-aligned) ----
    char* base = (char*)d_ws;
    size_t o = 0;
    ushort* hch  = (ushort*)(base + o); o += (size_t)NN * C3 * 2;
    ushort* tgb  = (ushort*)(base + o); o += (size_t)NN * 128 * 2;    // a1 overlay
    ushort* tcb  = (ushort*)(base + o); o += (size_t)NN * 128 * 2;
    ushort* tsb  = (ushort*)(base + o); o += (size_t)NN * 128 * 2;
    ushort* xb   = (ushort*)(base + o); o += (size_t)(NN + 1) * 128 * 2;  // +ZROW
    ushort* esrc = (ushort*)(base + o); o += ((size_t)(EE + NN) * 2 + 15) & ~15ull;
    int*    offs = (int*)(base + o);    o += (size_t)(NN + 16) * 4;
    float*  as_  = (float*)(base + o);  o += (size_t)NN * 4;
    float*  ad_  = (float*)(base + o);  o += (size_t)NN * 4;
    float*  dinv = (float*)(base + o);  o += (size_t)NN * 4;
    // --- zero-init region: bcnt only ---
    int*    bcnt = (int*)(base + o);    o += 128 * 4;
    // --- end zero region ---
    float*  pS   = (float*)(base + o);  o += (size_t)NBLK * C3 * 4;   // written fully
    float*  pQ   = (float*)(base + o);  o += (size_t)NBLK * C3 * 4;
    float*  scale= (float*)(base + o);  o += C3 * 4;
    float*  shift= (float*)(base + o);  o += C3 * 4;
    float*  w_as = (float*)(base + o);  o += 128 * 4;
    float*  w_ad = (float*)(base + o);  o += 128 * 4;
    ushort* btg  = (ushort*)(base + o); o += 128 * 128 * 2;
    ushort* btc  = (ushort*)(base + o); o += 128 * 128 * 2;
    ushort* btsg = (ushort*)(base + o); o += 128 * 256 * 2;
    ushort* bt1  = (ushort*)(base + o); o += 256 * 384 * 2;
    ushort* bt2  = (ushort*)(base + o); o += 128 * 256 * 2;
    ushort* bt3  = (ushort*)(base + o); o += 48 * 128 * 2;
    // overlays (temporally disjoint)
    ushort* a1 = tgb;                        // NN*256 ushorts (tgb+tcb)
    uint*   ebuf = (uint*)hch;               // 6.4MB; hch first written by k_gemm_prod

    hipMemsetAsync(bcnt, 0, 128 * 4, stream);

    // 1. bucket sort + weight prep (merged)
    k_bucketw<<<BK_BLKS + 817, 1024, 0, stream>>>(
        e_src, e_dst, bcnt, ebuf,
        W_gat, W_gcn, W_sage_l, W_sage_r, W1, W2, W3,
        att_src, att_dst, w_as, w_ad, btg, btc, btsg, bt1, bt2, bt3);

    // 2. CSR build (deg+scan+scatter) + x split (merged)
    k_csrx<<<NBUCK + SXB, 1024, 0, stream>>>(
        bcnt, ebuf, offs, dinv, esrc,
        x, w_as, w_ad, xb, as_, ad_);

    // 3. gather (16-lane quads, 2-deep pipeline)
    k_gather<<<(NN + 15) / 16, 256, 0, stream>>>(
        esrc, offs, as_, ad_, dinv, xb, tgb, tcb, tsb);

    // 4. producers: one launch, privatized BN partials
    k_gemm_prod<<<dim3(NBLK, 1, 3), 256, 0, stream>>>(
        tgb, tcb, tsb, xb, btg, btc, btsg,
        b_gat, b_gcn, b_sage_l, pS, pQ, hch);

    // 5. BN fold (4 threads/col partials reduce)
    k_bn_final<<<6, 256, 0, stream>>>(pS, pQ, gamma, beta, scale, shift);

    // 6. MLP L1 (BN+relu at afrag, 2 col-blocks — R7 best config)
    k_gemm2<8, 3, 1, 1><<<dim3(2, NBLK), 256, 0, stream>>>(
        hch, 384, bt1, NN, 0, b1, nullptr, 0, a1, 256, 256, scale, shift);

    // 7. MLP L2+L3 fused (a2 in LDS, fp32 out)
    k_gemm23<<<NBLK, 256, 0, stream>>>(a1, bt2, bt3, b2, b3, (float*)d_out);
}